// Round 1
// baseline (798.059 us; speedup 1.0000x reference)
//
#include <hip/hip_runtime.h>
#include <hip/hip_bf16.h>

// GCN forward: 2x GCNConv(64->64) + ReLU between, then Linear(64->2).
// N=100000 nodes, E=1250000 edges, F=64.
//
// Pipeline (all on `stream`):
//  1. deg init (dinv[i]=1), edge atomic add, rsqrt          -> dinv[N]
//  2. h   = x @ W1                                          -> bufA
//  3. agg1[i] = b1 + dinv[i]^2 * h[i]                       -> bufB
//  4. scatter: agg1[dst] += dinv[s]*dinv[d] * h[src]        (atomics)
//  5. h2  = relu(agg1) @ W2                                 -> bufA (reuse)
//  6. agg2[i] = b2 + dinv[i]^2 * h2[i]                      -> bufB (reuse)
//  7. scatter: agg2[dst] += dinv[s]*dinv[d] * h2[src]
//  8. out = agg2 @ Wlin + blin                              -> d_out [N,2]

#define FDIM 64

__global__ __launch_bounds__(256) void k_deg_init(float* __restrict__ deg, int n) {
    int i = blockIdx.x * blockDim.x + threadIdx.x;
    int stride = gridDim.x * blockDim.x;
    for (; i < n; i += stride) deg[i] = 1.0f;   // self-loop
}

__global__ __launch_bounds__(256) void k_deg_scatter(const int* __restrict__ dst,
                                                     float* __restrict__ deg, int nE) {
    int i = blockIdx.x * blockDim.x + threadIdx.x;
    int stride = gridDim.x * blockDim.x;
    for (; i < nE; i += stride) atomicAdd(&deg[dst[i]], 1.0f);
}

__global__ __launch_bounds__(256) void k_dinv(float* __restrict__ deg, int n) {
    int i = blockIdx.x * blockDim.x + threadIdx.x;
    int stride = gridDim.x * blockDim.x;
    for (; i < n; i += stride) deg[i] = rsqrtf(fmaxf(deg[i], 1.0f));
}

// Y[row][f] = sum_k act(X[row][k]) * W[k][f]  ; one wave per row, lane = f.
__global__ __launch_bounds__(256) void k_gemm64(const float* __restrict__ X,
                                                const float* __restrict__ W,
                                                float* __restrict__ Y, int n, int relu) {
    __shared__ float Wl[FDIM * FDIM];
    for (int i = threadIdx.x; i < FDIM * FDIM; i += blockDim.x) Wl[i] = W[i];
    __syncthreads();
    int lane = threadIdx.x & 63;
    int wave = (blockIdx.x * blockDim.x + threadIdx.x) >> 6;
    int nw   = (gridDim.x * blockDim.x) >> 6;
    for (int row = wave; row < n; row += nw) {
        float xv = X[(size_t)row * FDIM + lane];
        if (relu) xv = fmaxf(xv, 0.0f);
        float acc = 0.0f;
#pragma unroll
        for (int k = 0; k < FDIM; ++k) {
            float xk = __shfl(xv, k);
            acc = fmaf(xk, Wl[k * FDIM + lane], acc);
        }
        Y[(size_t)row * FDIM + lane] = acc;
    }
}

// agg[i][f] = b[f] + dinv[i]^2 * h[i][f]
__global__ __launch_bounds__(256) void k_init_agg(const float* __restrict__ H,
                                                  const float* __restrict__ dinv,
                                                  const float* __restrict__ b,
                                                  float* __restrict__ agg, int n) {
    int idx = blockIdx.x * blockDim.x + threadIdx.x;
    int stride = gridDim.x * blockDim.x;
    int total = n * FDIM;
    for (; idx < total; idx += stride) {
        int i = idx >> 6;
        int f = idx & 63;
        float di = dinv[i];
        agg[idx] = b[f] + di * di * H[idx];
    }
}

// one wave per edge; lane = feature
__global__ __launch_bounds__(256) void k_scatter(const float* __restrict__ H,
                                                 const float* __restrict__ dinv,
                                                 const int* __restrict__ src,
                                                 const int* __restrict__ dst,
                                                 float* __restrict__ out, int nE) {
    int lane = threadIdx.x & 63;
    int wave = (blockIdx.x * blockDim.x + threadIdx.x) >> 6;
    int nw   = (gridDim.x * blockDim.x) >> 6;
    for (int e = wave; e < nE; e += nw) {
        int s = src[e];
        int d = dst[e];
        float nrm = dinv[s] * dinv[d];
        float v = H[(size_t)s * FDIM + lane] * nrm;
        atomicAdd(&out[(size_t)d * FDIM + lane], v);
    }
}

// out[row][c] = sum_k A[row][k]*Wlin[k][c] + blin[c], C=2; one wave per row
__global__ __launch_bounds__(256) void k_head(const float* __restrict__ A,
                                              const float* __restrict__ Wlin,
                                              const float* __restrict__ blin,
                                              float* __restrict__ out, int n) {
    int lane = threadIdx.x & 63;
    int wave = (blockIdx.x * blockDim.x + threadIdx.x) >> 6;
    int nw   = (gridDim.x * blockDim.x) >> 6;
    for (int row = wave; row < n; row += nw) {
        float v  = A[(size_t)row * FDIM + lane];
        float p0 = v * Wlin[lane * 2 + 0];
        float p1 = v * Wlin[lane * 2 + 1];
#pragma unroll
        for (int m = 32; m >= 1; m >>= 1) {
            p0 += __shfl_xor(p0, m);
            p1 += __shfl_xor(p1, m);
        }
        if (lane == 0) {
            out[(size_t)row * 2 + 0] = p0 + blin[0];
            out[(size_t)row * 2 + 1] = p1 + blin[1];
        }
    }
}

extern "C" void kernel_launch(void* const* d_in, const int* in_sizes, int n_in,
                              void* d_out, int out_size, void* d_ws, size_t ws_size,
                              hipStream_t stream) {
    const float* x     = (const float*)d_in[0];
    const int*   ei    = (const int*)d_in[1];   // [2, E] int32
    // d_in[2] = batch (unused)
    const float* W1    = (const float*)d_in[3];
    const float* b1    = (const float*)d_in[4];
    const float* W2    = (const float*)d_in[5];
    const float* b2    = (const float*)d_in[6];
    const float* Wlin  = (const float*)d_in[7];
    const float* blin  = (const float*)d_in[8];
    float* out = (float*)d_out;

    const int n  = in_sizes[0] / FDIM;   // 100000
    const int nE = in_sizes[1] / 2;      // 1250000
    const int* src = ei;
    const int* dst = ei + nE;

    // workspace layout (fp32): dinv[nPad], bufA[n*64], bufB[n*64]
    int nPad = ((n + 1023) / 1024) * 1024;
    float* dinv = (float*)d_ws;
    float* bufA = dinv + nPad;
    float* bufB = bufA + (size_t)n * FDIM;

    const int TB = 256;
    int blkN  = min((n + TB - 1) / TB, 2048);
    int blkE  = min((nE + TB - 1) / TB, 2048);
    int blkNF = min((n * FDIM / 4 + TB - 1) / TB, 2048);
    int blkWaveRow = 1024;   // 4096 waves for wave-per-row kernels
    int blkWaveEdge = 2048;  // 8192 waves for wave-per-edge scatter

    // 1. degrees -> dinv
    k_deg_init<<<blkN, TB, 0, stream>>>(dinv, n);
    k_deg_scatter<<<blkE, TB, 0, stream>>>(dst, dinv, nE);
    k_dinv<<<blkN, TB, 0, stream>>>(dinv, n);

    // layer 1
    k_gemm64<<<blkWaveRow, TB, 0, stream>>>(x, W1, bufA, n, 0);
    k_init_agg<<<2048, TB, 0, stream>>>(bufA, dinv, b1, bufB, n);
    k_scatter<<<blkWaveEdge, TB, 0, stream>>>(bufA, dinv, src, dst, bufB, nE);

    // layer 2 (relu folded into gemm load)
    k_gemm64<<<blkWaveRow, TB, 0, stream>>>(bufB, W2, bufA, n, 1);
    k_init_agg<<<2048, TB, 0, stream>>>(bufA, dinv, b2, bufB, n);
    k_scatter<<<blkWaveEdge, TB, 0, stream>>>(bufA, dinv, src, dst, bufB, nE);

    // head
    k_head<<<blkWaveRow, TB, 0, stream>>>(bufB, Wlin, blin, out, n);

    (void)blkNF; (void)ws_size; (void)n_in; (void)out_size;
}

// Round 2
// 551.519 us; speedup vs baseline: 1.4470x; 1.4470x over previous
//
#include <hip/hip_runtime.h>
#include <hip/hip_bf16.h>

// GCN forward: 2x GCNConv(64->64) + ReLU between, then Linear(64->2).
// N=100000 nodes, E=1250000 edges, F=64.
//
// Round 2: replace float-atomic scatter (320 MB HBM write-through per layer)
// with CSR gather. Build CSR by dst once per call (hist -> scan -> fill),
// then each layer aggregates with zero atomics and one 256B write per node.
//
// Pipeline:
//  1. cnt=0; hist(dst); 3-kernel exclusive scan -> rowptr; dinv from degree;
//     cursor=rowptr; fill col[] (src sorted by dst)
//  2. bufA = x @ W1
//  3. bufB[i] = b1 + dinv_i*(dinv_i*bufA[i] + sum_{s in N(i)} dinv_s*bufA[s])
//  4. bufA = relu(bufB) @ W2
//  5. out[i][c] = blin[c] + sum_f Wlin[f][c]*(b2+dinv_i*(...))   (gather+head fused)

#define FDIM 64

__global__ __launch_bounds__(256) void k_zero_int(int* __restrict__ p, int n) {
    int i = blockIdx.x * blockDim.x + threadIdx.x;
    int stride = gridDim.x * blockDim.x;
    for (; i < n; i += stride) p[i] = 0;
}

__global__ __launch_bounds__(256) void k_hist(const int* __restrict__ dst,
                                              int* __restrict__ cnt, int nE) {
    int i = blockIdx.x * blockDim.x + threadIdx.x;
    int stride = gridDim.x * blockDim.x;
    for (; i < nE; i += stride) atomicAdd(&cnt[dst[i]], 1);
}

// block b sums cnt[b*1024 .. b*1024+1023] -> bsum[b]
__global__ __launch_bounds__(256) void k_scan1(const int* __restrict__ cnt,
                                               int* __restrict__ bsum, int n) {
    int b = blockIdx.x, t = threadIdx.x;
    int base = b * 1024 + t * 4;
    int s = 0;
#pragma unroll
    for (int j = 0; j < 4; ++j) { int idx = base + j; if (idx < n) s += cnt[idx]; }
#pragma unroll
    for (int off = 32; off >= 1; off >>= 1) s += __shfl_xor(s, off);
    __shared__ int wt[4];
    int lane = t & 63, w = t >> 6;
    if (lane == 0) wt[w] = s;
    __syncthreads();
    if (t == 0) bsum[b] = wt[0] + wt[1] + wt[2] + wt[3];
}

// single block: exclusive scan of bsum[0..nb), nb <= 256
__global__ __launch_bounds__(256) void k_scan2(int* __restrict__ bsum, int nb) {
    __shared__ int sm[256];
    int t = threadIdx.x;
    int v = (t < nb) ? bsum[t] : 0;
    sm[t] = v;
    __syncthreads();
    for (int off = 1; off < 256; off <<= 1) {
        int x = (t >= off) ? sm[t - off] : 0;
        __syncthreads();
        sm[t] += x;
        __syncthreads();
    }
    if (t < nb) bsum[t] = sm[t] - v;
}

// block b: exclusive scan of its 1024 counts + bsum[b] -> rowptr
__global__ __launch_bounds__(256) void k_scan3(const int* __restrict__ cnt,
                                               const int* __restrict__ bsum,
                                               int* __restrict__ rowptr, int n, int nE) {
    int b = blockIdx.x, t = threadIdx.x;
    int base = b * 1024 + t * 4;
    int v[4];
    int run = 0;
#pragma unroll
    for (int j = 0; j < 4; ++j) {
        int idx = base + j;
        int c = (idx < n) ? cnt[idx] : 0;
        v[j] = run;
        run += c;
    }
    int lane = t & 63, w = t >> 6;
    int inc = run;
#pragma unroll
    for (int off = 1; off < 64; off <<= 1) {
        int x = __shfl_up(inc, off);
        if (lane >= off) inc += x;
    }
    __shared__ int wt[4];
    if (lane == 63) wt[w] = inc;
    __syncthreads();
    int woff = 0;
    for (int i = 0; i < w; ++i) woff += wt[i];
    int gbase = bsum[b] + woff + (inc - run);
#pragma unroll
    for (int j = 0; j < 4; ++j) {
        int idx = base + j;
        if (idx < n) rowptr[idx] = gbase + v[j];
    }
    if (b == 0 && t == 0) rowptr[n] = nE;
}

// dinv[i] = rsqrt(indeg+1); cursor[i] = rowptr[i]
__global__ __launch_bounds__(256) void k_dinv_cursor(const int* __restrict__ rowptr,
                                                     float* __restrict__ dinv,
                                                     int* __restrict__ cursor, int n) {
    int i = blockIdx.x * blockDim.x + threadIdx.x;
    int stride = gridDim.x * blockDim.x;
    for (; i < n; i += stride) {
        int beg = rowptr[i], end = rowptr[i + 1];
        dinv[i] = rsqrtf((float)(end - beg + 1));
        cursor[i] = beg;
    }
}

__global__ __launch_bounds__(256) void k_fill(const int* __restrict__ src,
                                              const int* __restrict__ dst,
                                              int* __restrict__ cursor,
                                              int* __restrict__ col, int nE) {
    int i = blockIdx.x * blockDim.x + threadIdx.x;
    int stride = gridDim.x * blockDim.x;
    for (; i < nE; i += stride) {
        int d = dst[i];
        int pos = atomicAdd(&cursor[d], 1);
        col[pos] = src[i];
    }
}

// Y[row][f] = sum_k act(X[row][k]) * W[k][f]  ; one wave per row, lane = f.
__global__ __launch_bounds__(256) void k_gemm64(const float* __restrict__ X,
                                                const float* __restrict__ W,
                                                float* __restrict__ Y, int n, int relu) {
    __shared__ float Wl[FDIM * FDIM];
    for (int i = threadIdx.x; i < FDIM * FDIM; i += blockDim.x) Wl[i] = W[i];
    __syncthreads();
    int lane = threadIdx.x & 63;
    int wave = (blockIdx.x * blockDim.x + threadIdx.x) >> 6;
    int nw   = (gridDim.x * blockDim.x) >> 6;
    for (int row = wave; row < n; row += nw) {
        float xv = X[(size_t)row * FDIM + lane];
        if (relu) xv = fmaxf(xv, 0.0f);
        float acc = 0.0f;
#pragma unroll
        for (int k = 0; k < FDIM; ++k) {
            float xk = __shfl(xv, k);
            acc = fmaf(xk, Wl[k * FDIM + lane], acc);
        }
        Y[(size_t)row * FDIM + lane] = acc;
    }
}

// out[i][f] = b[f] + dinv_i*(dinv_i*H[i][f] + sum_{k in [beg,end)} dinv[col[k]]*H[col[k]][f])
__global__ __launch_bounds__(256) void k_gather(const float* __restrict__ H,
                                                const float* __restrict__ dinv,
                                                const int* __restrict__ rowptr,
                                                const int* __restrict__ col,
                                                const float* __restrict__ b,
                                                float* __restrict__ out, int n) {
    int lane = threadIdx.x & 63;
    int wave = (blockIdx.x * blockDim.x + threadIdx.x) >> 6;
    int nw   = (gridDim.x * blockDim.x) >> 6;
    for (int row = wave; row < n; row += nw) {
        float dd  = dinv[row];
        int beg = rowptr[row], end = rowptr[row + 1];
        float acc = dd * H[(size_t)row * FDIM + lane];
        for (int k = beg; k < end; ++k) {
            int s = col[k];
            acc = fmaf(dinv[s], H[(size_t)s * FDIM + lane], acc);
        }
        out[(size_t)row * FDIM + lane] = fmaf(dd, acc, b[lane]);
    }
}

// gather for layer 2 fused with the [64->2] linear head
__global__ __launch_bounds__(256) void k_gather_head(const float* __restrict__ H,
                                                     const float* __restrict__ dinv,
                                                     const int* __restrict__ rowptr,
                                                     const int* __restrict__ col,
                                                     const float* __restrict__ b,
                                                     const float* __restrict__ Wlin,
                                                     const float* __restrict__ blin,
                                                     float* __restrict__ out, int n) {
    int lane = threadIdx.x & 63;
    int wave = (blockIdx.x * blockDim.x + threadIdx.x) >> 6;
    int nw   = (gridDim.x * blockDim.x) >> 6;
    for (int row = wave; row < n; row += nw) {
        float dd  = dinv[row];
        int beg = rowptr[row], end = rowptr[row + 1];
        float acc = dd * H[(size_t)row * FDIM + lane];
        for (int k = beg; k < end; ++k) {
            int s = col[k];
            acc = fmaf(dinv[s], H[(size_t)s * FDIM + lane], acc);
        }
        float v = fmaf(dd, acc, b[lane]);
        float p0 = v * Wlin[lane * 2 + 0];
        float p1 = v * Wlin[lane * 2 + 1];
#pragma unroll
        for (int m = 32; m >= 1; m >>= 1) {
            p0 += __shfl_xor(p0, m);
            p1 += __shfl_xor(p1, m);
        }
        if (lane == 0) {
            out[(size_t)row * 2 + 0] = p0 + blin[0];
            out[(size_t)row * 2 + 1] = p1 + blin[1];
        }
    }
}

extern "C" void kernel_launch(void* const* d_in, const int* in_sizes, int n_in,
                              void* d_out, int out_size, void* d_ws, size_t ws_size,
                              hipStream_t stream) {
    const float* x    = (const float*)d_in[0];
    const int*   ei   = (const int*)d_in[1];   // [2, E] int32
    const float* W1   = (const float*)d_in[3];
    const float* b1   = (const float*)d_in[4];
    const float* W2   = (const float*)d_in[5];
    const float* b2   = (const float*)d_in[6];
    const float* Wlin = (const float*)d_in[7];
    const float* blin = (const float*)d_in[8];
    float* out = (float*)d_out;

    const int n  = in_sizes[0] / FDIM;   // 100000
    const int nE = in_sizes[1] / 2;      // 1250000
    const int* src = ei;
    const int* dst = ei + nE;

    // workspace layout (all 4B elems, 1024-elem aligned regions):
    int nPad = ((n + 1024) / 1024) * 1024;           // >= n+1
    float* dinv   = (float*)d_ws;                    // [nPad]
    int*   rowptr = (int*)(dinv + nPad);             // [nPad] (n+1 used)
    int*   cnt    = rowptr + nPad;                   // [nPad] reused as cursor
    int*   bsum   = cnt + nPad;                      // [1024]
    int*   col    = bsum + 1024;                     // [nE]
    int    nEPad  = ((nE + 1023) / 1024) * 1024;
    float* bufA   = (float*)(col + nEPad);           // [n*64]
    float* bufB   = bufA + (size_t)n * FDIM;         // [n*64]

    const int TB = 256;
    int blkN  = min((n + TB - 1) / TB, 2048);
    int blkE  = min((nE + TB - 1) / TB, 2048);
    int nb    = (n + 1023) / 1024;                   // scan blocks (98)

    // CSR build
    k_zero_int<<<blkN, TB, 0, stream>>>(cnt, n);
    k_hist<<<blkE, TB, 0, stream>>>(dst, cnt, nE);
    k_scan1<<<nb, TB, 0, stream>>>(cnt, bsum, n);
    k_scan2<<<1, TB, 0, stream>>>(bsum, nb);
    k_scan3<<<nb, TB, 0, stream>>>(cnt, bsum, rowptr, n, nE);
    k_dinv_cursor<<<blkN, TB, 0, stream>>>(rowptr, dinv, cnt, n);  // cnt becomes cursor
    k_fill<<<blkE, TB, 0, stream>>>(src, dst, cnt, col, nE);

    // layer 1
    k_gemm64<<<1024, TB, 0, stream>>>(x, W1, bufA, n, 0);
    k_gather<<<2048, TB, 0, stream>>>(bufA, dinv, rowptr, col, b1, bufB, n);

    // layer 2 + head
    k_gemm64<<<1024, TB, 0, stream>>>(bufB, W2, bufA, n, 1);
    k_gather_head<<<2048, TB, 0, stream>>>(bufA, dinv, rowptr, col, b2, Wlin, blin, out, n);

    (void)ws_size; (void)n_in; (void)out_size;
}

// Round 3
// 433.585 us; speedup vs baseline: 1.8406x; 1.2720x over previous
//
#include <hip/hip_runtime.h>
#include <hip/hip_bf16.h>

// GCN forward: 2x GCNConv(64->64) + ReLU between, then Linear(64->2).
// N=100000 nodes, E=1250000 edges, F=64.
//
// Round 3: gathers were latency-bound (1.37 TB/s, VALU 17%). Unroll edge loop
// x4 with wave-uniform (scalar) col/dinv loads and 4 independent H-row loads
// in flight. Fuse dinv/cursor init into scan3.

#define FDIM 64

__global__ __launch_bounds__(256) void k_zero_int(int* __restrict__ p, int n) {
    int i = blockIdx.x * blockDim.x + threadIdx.x;
    int stride = gridDim.x * blockDim.x;
    for (; i < n; i += stride) p[i] = 0;
}

__global__ __launch_bounds__(256) void k_hist(const int* __restrict__ dst,
                                              int* __restrict__ cnt, int nE) {
    int i = blockIdx.x * blockDim.x + threadIdx.x;
    int stride = gridDim.x * blockDim.x;
    for (; i < nE; i += stride) atomicAdd(&cnt[dst[i]], 1);
}

// block b sums cnt[b*1024 .. b*1024+1023] -> bsum[b]
__global__ __launch_bounds__(256) void k_scan1(const int* __restrict__ cnt,
                                               int* __restrict__ bsum, int n) {
    int b = blockIdx.x, t = threadIdx.x;
    int base = b * 1024 + t * 4;
    int s = 0;
#pragma unroll
    for (int j = 0; j < 4; ++j) { int idx = base + j; if (idx < n) s += cnt[idx]; }
#pragma unroll
    for (int off = 32; off >= 1; off >>= 1) s += __shfl_xor(s, off);
    __shared__ int wt[4];
    int lane = t & 63, w = t >> 6;
    if (lane == 0) wt[w] = s;
    __syncthreads();
    if (t == 0) bsum[b] = wt[0] + wt[1] + wt[2] + wt[3];
}

// single block: exclusive scan of bsum[0..nb), nb <= 256
__global__ __launch_bounds__(256) void k_scan2(int* __restrict__ bsum, int nb) {
    __shared__ int sm[256];
    int t = threadIdx.x;
    int v = (t < nb) ? bsum[t] : 0;
    sm[t] = v;
    __syncthreads();
    for (int off = 1; off < 256; off <<= 1) {
        int x = (t >= off) ? sm[t - off] : 0;
        __syncthreads();
        sm[t] += x;
        __syncthreads();
    }
    if (t < nb) bsum[t] = sm[t] - v;
}

// block b: exclusive scan of its 1024 counts + bsum[b] -> rowptr, cursor, dinv
__global__ __launch_bounds__(256) void k_scan3(const int* __restrict__ cnt,
                                               const int* __restrict__ bsum,
                                               int* __restrict__ rowptr,
                                               int* __restrict__ cursor,
                                               float* __restrict__ dinv,
                                               int n, int nE) {
    int b = blockIdx.x, t = threadIdx.x;
    int base = b * 1024 + t * 4;
    int v[4], c[4];
    int run = 0;
#pragma unroll
    for (int j = 0; j < 4; ++j) {
        int idx = base + j;
        c[j] = (idx < n) ? cnt[idx] : 0;
        v[j] = run;
        run += c[j];
    }
    int lane = t & 63, w = t >> 6;
    int inc = run;
#pragma unroll
    for (int off = 1; off < 64; off <<= 1) {
        int x = __shfl_up(inc, off);
        if (lane >= off) inc += x;
    }
    __shared__ int wt[4];
    if (lane == 63) wt[w] = inc;
    __syncthreads();
    int woff = 0;
    for (int i = 0; i < w; ++i) woff += wt[i];
    int gbase = bsum[b] + woff + (inc - run);
#pragma unroll
    for (int j = 0; j < 4; ++j) {
        int idx = base + j;
        if (idx < n) {
            int beg = gbase + v[j];
            rowptr[idx] = beg;
            cursor[idx] = beg;
            dinv[idx]   = rsqrtf((float)(c[j] + 1));
        }
    }
    if (b == 0 && t == 0) rowptr[n] = nE;
}

__global__ __launch_bounds__(256) void k_fill(const int* __restrict__ src,
                                              const int* __restrict__ dst,
                                              int* __restrict__ cursor,
                                              int* __restrict__ col, int nE) {
    int i = blockIdx.x * blockDim.x + threadIdx.x;
    int stride = gridDim.x * blockDim.x;
    for (; i < nE; i += stride) {
        int d = dst[i];
        int pos = atomicAdd(&cursor[d], 1);
        col[pos] = src[i];
    }
}

// Y[row][f] = sum_k act(X[row][k]) * W[k][f]  ; one wave per row, lane = f.
__global__ __launch_bounds__(256) void k_gemm64(const float* __restrict__ X,
                                                const float* __restrict__ W,
                                                float* __restrict__ Y, int n, int relu) {
    __shared__ float Wl[FDIM * FDIM];
    for (int i = threadIdx.x; i < FDIM * FDIM; i += blockDim.x) Wl[i] = W[i];
    __syncthreads();
    int lane = threadIdx.x & 63;
    int wave = (blockIdx.x * blockDim.x + threadIdx.x) >> 6;
    int nw   = (gridDim.x * blockDim.x) >> 6;
    for (int row = wave; row < n; row += nw) {
        float xv = X[(size_t)row * FDIM + lane];
        if (relu) xv = fmaxf(xv, 0.0f);
        float acc = 0.0f;
#pragma unroll
        for (int k = 0; k < FDIM; ++k) {
            float xk = __shfl(xv, k);
            acc = fmaf(xk, Wl[k * FDIM + lane], acc);
        }
        Y[(size_t)row * FDIM + lane] = acc;
    }
}

// out[i][f] = b[f] + dinv_i*(dinv_i*H[i][f] + sum_{k} dinv[col[k]]*H[col[k]][f])
// HEAD=0: write [n,64] features. HEAD=1: fold in Wlin/blin, write [n,2].
template <int HEAD>
__global__ __launch_bounds__(256) void k_gather_t(const float* __restrict__ H,
                                                  const float* __restrict__ dinv,
                                                  const int* __restrict__ rowptr,
                                                  const int* __restrict__ col,
                                                  const float* __restrict__ b,
                                                  const float* __restrict__ Wlin,
                                                  const float* __restrict__ blin,
                                                  float* __restrict__ out, int n) {
    int lane = threadIdx.x & 63;
    int wid  = __builtin_amdgcn_readfirstlane((blockIdx.x * blockDim.x + threadIdx.x) >> 6);
    int nw   = (gridDim.x * blockDim.x) >> 6;
    for (int row = wid; row < n; row += nw) {
        float dd  = dinv[row];
        int beg = rowptr[row], end = rowptr[row + 1];
        float acc = dd * H[(size_t)row * FDIM + lane];
        int k = beg;
        for (; k + 4 <= end; k += 4) {
            int s0 = col[k + 0], s1 = col[k + 1], s2 = col[k + 2], s3 = col[k + 3];
            float w0 = dinv[s0], w1 = dinv[s1], w2 = dinv[s2], w3 = dinv[s3];
            float h0 = H[(size_t)s0 * FDIM + lane];
            float h1 = H[(size_t)s1 * FDIM + lane];
            float h2 = H[(size_t)s2 * FDIM + lane];
            float h3 = H[(size_t)s3 * FDIM + lane];
            acc = fmaf(w0, h0, acc);
            acc = fmaf(w1, h1, acc);
            acc = fmaf(w2, h2, acc);
            acc = fmaf(w3, h3, acc);
        }
        for (; k < end; ++k) {
            int s = col[k];
            acc = fmaf(dinv[s], H[(size_t)s * FDIM + lane], acc);
        }
        float v = fmaf(dd, acc, b[lane]);
        if (HEAD == 0) {
            out[(size_t)row * FDIM + lane] = v;
        } else {
            float p0 = v * Wlin[lane * 2 + 0];
            float p1 = v * Wlin[lane * 2 + 1];
#pragma unroll
            for (int m = 32; m >= 1; m >>= 1) {
                p0 += __shfl_xor(p0, m);
                p1 += __shfl_xor(p1, m);
            }
            if (lane == 0) {
                out[(size_t)row * 2 + 0] = p0 + blin[0];
                out[(size_t)row * 2 + 1] = p1 + blin[1];
            }
        }
    }
}

extern "C" void kernel_launch(void* const* d_in, const int* in_sizes, int n_in,
                              void* d_out, int out_size, void* d_ws, size_t ws_size,
                              hipStream_t stream) {
    const float* x    = (const float*)d_in[0];
    const int*   ei   = (const int*)d_in[1];   // [2, E] int32
    const float* W1   = (const float*)d_in[3];
    const float* b1   = (const float*)d_in[4];
    const float* W2   = (const float*)d_in[5];
    const float* b2   = (const float*)d_in[6];
    const float* Wlin = (const float*)d_in[7];
    const float* blin = (const float*)d_in[8];
    float* out = (float*)d_out;

    const int n  = in_sizes[0] / FDIM;   // 100000
    const int nE = in_sizes[1] / 2;      // 1250000
    const int* src = ei;
    const int* dst = ei + nE;

    // workspace layout (all 4B elems, 1024-elem aligned regions):
    int nPad = ((n + 1024) / 1024) * 1024;           // >= n+1
    float* dinv   = (float*)d_ws;                    // [nPad]
    int*   rowptr = (int*)(dinv + nPad);             // [nPad] (n+1 used)
    int*   cnt    = rowptr + nPad;                   // [nPad] reused as cursor
    int*   bsum   = cnt + nPad;                      // [1024]
    int*   col    = bsum + 1024;                     // [nE]
    int    nEPad  = ((nE + 1023) / 1024) * 1024;
    float* bufA   = (float*)(col + nEPad);           // [n*64]
    float* bufB   = bufA + (size_t)n * FDIM;         // [n*64]

    const int TB = 256;
    int blkN  = min((n + TB - 1) / TB, 2048);
    int blkE  = min((nE + TB - 1) / TB, 4096);
    int nb    = (n + 1023) / 1024;                   // scan blocks (98)

    // CSR build
    k_zero_int<<<blkN, TB, 0, stream>>>(cnt, n);
    k_hist<<<blkE, TB, 0, stream>>>(dst, cnt, nE);
    k_scan1<<<nb, TB, 0, stream>>>(cnt, bsum, n);
    k_scan2<<<1, TB, 0, stream>>>(bsum, nb);
    k_scan3<<<nb, TB, 0, stream>>>(cnt, bsum, rowptr, cnt, dinv, n, nE);  // cnt -> cursor
    k_fill<<<blkE, TB, 0, stream>>>(src, dst, cnt, col, nE);

    // layer 1
    k_gemm64<<<1024, TB, 0, stream>>>(x, W1, bufA, n, 0);
    k_gather_t<0><<<2048, TB, 0, stream>>>(bufA, dinv, rowptr, col, b1, nullptr, nullptr, bufB, n);

    // layer 2 + head
    k_gemm64<<<1024, TB, 0, stream>>>(bufB, W2, bufA, n, 1);
    k_gather_t<1><<<2048, TB, 0, stream>>>(bufA, dinv, rowptr, col, b2, Wlin, blin, out, n);

    (void)ws_size; (void)n_in; (void)out_size;
}